// Round 1
// baseline (933.387 us; speedup 1.0000x reference)
//
#include <hip/hip_runtime.h>

// Problem constants (B=8, C=64, W=496, H=432)
#define WH      214272            // 496*432 pixels per (b,c) plane
#define GPB     53568             // WH/4 float4 groups per plane (mult of 64)
#define TOTAL4  (512*GPB)         // all float4 elements = 27,426,816
#define CHUNKS  (TOTAL4/64)       // 64-float4 (1 KB/wave) chunks = 428544
#define CPP     837               // chunks per plane (GPB/64)
#define SEG     9                 // chunks per segment; 837 = 9*93 -> plane-aligned
#define SPP     93                // segments per plane
#define NSEG    (512*SPP)         // 47616 total segments

#define STATS_BLOCKS 2048         // 8 blocks/CU
#define SCALE_BLOCKS 2048         // 8 blocks/CU

typedef float floatx4 __attribute__((ext_vector_type(4)));

// ---------------- K1: per-channel sum/sumsq + per-batch mask count ----------------
// Globally FRONT->BACK streaming: waves stride over 9-chunk plane-aligned segments,
// so the machine-wide read order is sequential in address. At kernel end the L3
// (256 MB) holds the contiguous ARRAY TAIL — exactly what k_scale (reverse walk)
// consumes first, before any miss can evict it. Segment stays within one plane
// (93 segs/plane) -> channel is wave-uniform -> scalar accumulators; butterfly
// reduce + 2 global atomics per 9KB segment (~95k atomics total, negligible).
// Mask: occ zeroes all channels of a pixel together -> channel 0 alone decides.
__global__ __launch_bounds__(256, 8) void k_stats(const floatx4* __restrict__ x4,
                                                  float* __restrict__ gsum,
                                                  float* __restrict__ gsq,
                                                  int* __restrict__ gn) {
    const int lane = threadIdx.x & 63;
    const int gw   = blockIdx.x * 4 + (threadIdx.x >> 6);   // global wave id
    const int nw   = STATS_BLOCKS * 4;                      // 8192 waves

    for (int seg = gw; seg < NSEG; seg += nw) {
        const int plane = (int)((unsigned)seg / SPP);       // wave-uniform
        const bool isC0 = (plane & 63) == 0;

        float s = 0.f, q = 0.f;
        int cnt = 0;
        const floatx4* p = x4 + (size_t)seg * (SEG * 64) + lane;
#pragma unroll
        for (int k = 0; k < SEG; ++k) {
            const floatx4 v = p[k * 64];
            s += (v.x + v.y) + (v.z + v.w);
            q = fmaf(v.w, v.w, fmaf(v.z, v.z, fmaf(v.y, v.y, fmaf(v.x, v.x, q))));
            if (isC0) cnt += (v.x != 0.f) + (v.y != 0.f) + (v.z != 0.f) + (v.w != 0.f);
        }
#pragma unroll
        for (int m = 1; m < 64; m <<= 1) {
            s += __shfl_xor(s, m, 64);
            q += __shfl_xor(q, m, 64);
        }
        if (isC0) {
#pragma unroll
            for (int m = 1; m < 64; m <<= 1) cnt += __shfl_xor(cnt, m, 64);
        }
        if (lane == 0) {
            atomicAdd(&gsum[plane & 63], s);
            atomicAdd(&gsq[plane & 63], q);
            if (isC0) atomicAdd(&gn[plane >> 6], cnt);
        }
    }
}

// ---------------- K2: finalize (prologue) + out = x * inv[c], REVERSE order ----------
// k_stats streamed x front->back, so the array TAIL (~256MB) is L3-resident. Walking
// chunks in reverse consumes every resident line in the first ~32 iterations, before
// the first miss (front 182MB) can evict anything. NT loads/stores: x won't be
// re-read, out is write-once -> don't displace the resident tail.
__global__ __launch_bounds__(256, 8) void k_scale(const floatx4* __restrict__ x4,
                                                  floatx4* __restrict__ out4,
                                                  const float* __restrict__ gsum,
                                                  const float* __restrict__ gsq,
                                                  const int* __restrict__ gn) {
    __shared__ float sinv[64];
    const int tid = threadIdx.x;
    if (tid < 64) {
        const int c = tid;
        const float* x = (const float*)x4;
        int nb[8];
        int N = 0;
#pragma unroll
        for (int b = 0; b < 8; ++b) { nb[b] = gn[b]; N = max(N, nb[b]); }
        float total = gsum[c];
        float S2    = gsq[c];
#pragma unroll
        for (int b = 0; b < 8; ++b) {
            const float pad = (float)(N - nb[b]);
            const float x00 = x[(size_t)(b * 64 + c) * WH];
            total = fmaf(pad, x00, total);
            S2    = fmaf(pad, x00 * x00, S2);
        }
        const float count = (float)(8 * N);
        const float mean  = total / count;
        const float var   = S2 / count - mean * mean;
        sinv[c] = 1.0f / sqrtf(var + 0.001f);
    }
    __syncthreads();

    const int lane = tid & 63;
    const int gw   = blockIdx.x * 4 + (tid >> 6);   // 0..8191
    const int nw   = SCALE_BLOCKS * 4;
#pragma unroll 2
    for (int ch = CHUNKS - 1 - gw; ch >= 0; ch -= nw) {
        const int plane = (int)((unsigned)ch / CPP);      // wave-uniform
        const float inv = sinv[plane & 63];
        const size_t i = (size_t)ch * 64 + lane;
        floatx4 v = __builtin_nontemporal_load(&x4[i]);
        v.x *= inv; v.y *= inv; v.z *= inv; v.w *= inv;
        __builtin_nontemporal_store(v, &out4[i]);
    }
}

extern "C" void kernel_launch(void* const* d_in, const int* in_sizes, int n_in,
                              void* d_out, int out_size, void* d_ws, size_t ws_size,
                              hipStream_t stream) {
    const float* x  = (const float*)d_in[0];
    float* out      = (float*)d_out;
    float* wsf      = (float*)d_ws;
    float* gsum     = wsf;               // 64 floats
    float* gsq      = wsf + 64;          // 64 floats
    int*   gn       = (int*)(wsf + 128); // 8 ints

    (void)hipMemsetAsync(d_ws, 0, 136 * sizeof(float), stream);

    k_stats<<<STATS_BLOCKS, 256, 0, stream>>>((const floatx4*)x, gsum, gsq, gn);
    k_scale<<<SCALE_BLOCKS, 256, 0, stream>>>((const floatx4*)x, (floatx4*)out,
                                              gsum, gsq, gn);
}

// Round 2
// 790.441 us; speedup vs baseline: 1.1808x; 1.1808x over previous
//
#include <hip/hip_runtime.h>

// Problem constants (B=8, C=64, W=496, H=432)
#define WH      214272            // 496*432 pixels per (b,c) plane
#define GPB     53568             // WH/4 float4 groups per plane (mult of 64)
#define TOTAL4  (512*GPB)         // all float4 elements = 27,426,816
#define CHUNKS  (TOTAL4/64)       // 64-float4 (1 KB/wave) chunks = 428544
#define CPP     (GPB/64)          // chunks per plane = 837

#define STATS_BLOCKS 1024         // 4 blocks/CU
#define NWAVES (STATS_BLOCKS*4)   // 4096 stats waves
#define PER ((CHUNKS + NWAVES - 1)/NWAVES)   // 105 chunks per stats-wave run

#define SCALE_BLOCKS 2048         // 8 blocks/CU; wave PAIR mirrors one stats run

typedef float floatx4 __attribute__((ext_vector_type(4)));

// ---------------- K1: per-channel sum/sumsq + per-batch mask count ----------------
// ROUND-0 STRUCTURE (known-good): each wave owns a contiguous run of 105 1KB chunks.
// Within a plane-run the channel is wave-uniform -> scalar register accumulators,
// butterfly reduce + 2 atomics per plane-run (<=3 runs/wave). Mask: occ zeroes all
// channels of a pixel together -> channel 0 alone decides -> only c==0 planes count.
// Plain (allocating) loads: we WANT x's tail resident in L3 for k_scale.
__global__ __launch_bounds__(256, 4) void k_stats(const floatx4* __restrict__ x4,
                                                  float* __restrict__ gsum,
                                                  float* __restrict__ gsq,
                                                  int* __restrict__ gn) {
    const int lane = threadIdx.x & 63;
    const int gw   = blockIdx.x * 4 + (threadIdx.x >> 6);   // global wave id
    int c0 = gw * PER;
    const int c1 = min(c0 + PER, CHUNKS);

    while (c0 < c1) {
        const int plane = (int)((unsigned)c0 / CPP);        // wave-uniform
        const int run   = min(c1, (plane + 1) * CPP);       // end of this plane-run
        const bool isC0 = (plane & 63) == 0;

        float s = 0.f, q = 0.f;
        int cnt = 0;
        const floatx4* p = x4 + (size_t)c0 * 64 + lane;
        const int n = run - c0;
#pragma unroll 4
        for (int k = 0; k < n; ++k) {
            const floatx4 v = p[(size_t)k * 64];
            s += (v.x + v.y) + (v.z + v.w);
            q = fmaf(v.w, v.w, fmaf(v.z, v.z, fmaf(v.y, v.y, fmaf(v.x, v.x, q))));
            if (isC0) cnt += (v.x != 0.f) + (v.y != 0.f) + (v.z != 0.f) + (v.w != 0.f);
        }
#pragma unroll
        for (int m = 1; m < 64; m <<= 1) {
            s += __shfl_xor(s, m, 64);
            q += __shfl_xor(q, m, 64);
        }
        if (isC0) {
#pragma unroll
            for (int m = 1; m < 64; m <<= 1) cnt += __shfl_xor(cnt, m, 64);
        }
        if (lane == 0) {
            atomicAdd(&gsum[plane & 63], s);
            atomicAdd(&gsq[plane & 63], q);
            if (isC0) atomicAdd(&gn[plane >> 6], cnt);
        }
        c0 = run;
    }
}

// ---------------- K2: finalize (prologue) + out = x * inv[c], MIRRORED reverse ------
// At k_stats end, L3 holds the tail ~61% of EVERY stats run (all runs advanced in
// lockstep -> LRU recency is ordered by offset-within-run). Wave PAIR p mirrors stats
// run p and walks it tail-first (stride-2 interleave across the pair): all waves
// consume offset-104 lines first (globally most recent), popping the LRU stack from
// the top; misses (offsets < ~44) begin only after every resident line is consumed.
// NT load/store: x won't be re-read, out is write-once -> don't displace residents.
__global__ __launch_bounds__(256, 8) void k_scale(const floatx4* __restrict__ x4,
                                                  floatx4* __restrict__ out4,
                                                  const float* __restrict__ gsum,
                                                  const float* __restrict__ gsq,
                                                  const int* __restrict__ gn) {
    __shared__ float sinv[64];
    const int tid = threadIdx.x;
    if (tid < 64) {
        const int c = tid;
        const float* x = (const float*)x4;
        int nb[8];
        int N = 0;
#pragma unroll
        for (int b = 0; b < 8; ++b) { nb[b] = gn[b]; N = max(N, nb[b]); }
        float total = gsum[c];
        float S2    = gsq[c];
#pragma unroll
        for (int b = 0; b < 8; ++b) {
            const float pad = (float)(N - nb[b]);
            const float x00 = x[(size_t)(b * 64 + c) * WH];
            total = fmaf(pad, x00, total);
            S2    = fmaf(pad, x00 * x00, S2);
        }
        const float count = (float)(8 * N);
        const float mean  = total / count;
        const float var   = S2 / count - mean * mean;
        sinv[c] = 1.0f / sqrtf(var + 0.001f);
    }
    __syncthreads();

    const int lane = tid & 63;
    const int gw   = blockIdx.x * 4 + (tid >> 6);   // 0..8191
    const int run  = gw >> 1;                       // mirrors stats wave id 0..4095
    const int sub  = gw & 1;
    const int c0   = run * PER;
    const int c1   = min(c0 + PER, CHUNKS);
#pragma unroll 4
    for (int ch = c1 - 1 - sub; ch >= c0; ch -= 2) {
        const int plane = (int)((unsigned)ch / CPP);      // wave-uniform
        const float inv = sinv[plane & 63];
        const size_t i = (size_t)ch * 64 + lane;
        floatx4 v = __builtin_nontemporal_load(&x4[i]);
        v.x *= inv; v.y *= inv; v.z *= inv; v.w *= inv;
        __builtin_nontemporal_store(v, &out4[i]);
    }
}

extern "C" void kernel_launch(void* const* d_in, const int* in_sizes, int n_in,
                              void* d_out, int out_size, void* d_ws, size_t ws_size,
                              hipStream_t stream) {
    const float* x  = (const float*)d_in[0];
    float* out      = (float*)d_out;
    float* wsf      = (float*)d_ws;
    float* gsum     = wsf;               // 64 floats
    float* gsq      = wsf + 64;          // 64 floats
    int*   gn       = (int*)(wsf + 128); // 8 ints

    (void)hipMemsetAsync(d_ws, 0, 136 * sizeof(float), stream);

    k_stats<<<STATS_BLOCKS, 256, 0, stream>>>((const floatx4*)x, gsum, gsq, gn);
    k_scale<<<SCALE_BLOCKS, 256, 0, stream>>>((const floatx4*)x, (floatx4*)out,
                                              gsum, gsq, gn);
}